// Round 1
// baseline (1999.748 us; speedup 1.0000x reference)
//
#include <hip/hip_runtime.h>
#include <hip/hip_bf16.h>

typedef __attribute__((ext_vector_type(8))) short bf16x8;
typedef __attribute__((ext_vector_type(4))) float f32x4;

__device__ __forceinline__ ushort f2bf(float f) {
  union { float f; unsigned u; } v; v.f = f;
  unsigned r = v.u + 0x7fffu + ((v.u >> 16) & 1u);
  return (ushort)(r >> 16);
}

// ---------------- transpose + fp32->bf16 convert ----------------
// src: [B][R][C] fp32  ->  dst: [B][C][R] bf16
__global__ __launch_bounds__(256) void k_transpose_bf16(
    const float* __restrict__ src, ushort* __restrict__ dst, int R, int C) {
  __shared__ ushort tile[64][68];  // pad to 68 (136B row stride, 8B aligned)
  const int b = blockIdx.z;
  const size_t mat = (size_t)R * C;
  const float* s = src + (size_t)b * mat;
  ushort* d = dst + (size_t)b * mat;
  const int c0 = blockIdx.x * 64;
  const int r0 = blockIdx.y * 64;
  const int tx = threadIdx.x & 15;
  const int ty = threadIdx.x >> 4;
#pragma unroll
  for (int it = 0; it < 4; ++it) {
    const int r = ty + 16 * it;
    const float4 v = *reinterpret_cast<const float4*>(s + (size_t)(r0 + r) * C + (c0 + tx * 4));
    ushort4 u;
    u.x = f2bf(v.x); u.y = f2bf(v.y); u.z = f2bf(v.z); u.w = f2bf(v.w);
    *reinterpret_cast<ushort4*>(&tile[r][tx * 4]) = u;
  }
  __syncthreads();
#pragma unroll
  for (int it = 0; it < 4; ++it) {
    const int wy = ty + 16 * it;  // local output row (= input col)
    ushort4 u;
    u.x = tile[tx * 4 + 0][wy];
    u.y = tile[tx * 4 + 1][wy];
    u.z = tile[tx * 4 + 2][wy];
    u.w = tile[tx * 4 + 3][wy];
    *reinterpret_cast<ushort4*>(d + (size_t)(c0 + wy) * R + (r0 + tx * 4)) = u;
  }
}

// ---------------- GEMM1 fused: h = silu(x@w1) * (x@w3), bf16 out ----------------
#define BM 128
#define BN 128
#define BKE 64  // K elements per tile

__device__ __forceinline__ void xcd_map(int bid, int RT, int CT, int& r, int& c) {
  if ((RT & 7) == 0) {
    const int xcd = bid & 7, j = bid >> 3;
    r = xcd + 8 * (j / CT);
    c = j % CT;
  } else {
    r = bid / CT; c = bid % CT;
  }
}

__device__ __forceinline__ int expert_of(const int* g, int E, int m0) {
  int e = 0, base = 0;
  while (e < E - 1 && m0 >= base + g[e]) { base += g[e]; ++e; }
  return e;
}

__global__ __launch_bounds__(256) void k_gemm1_swiglu(
    const float* __restrict__ x,     // [T][D] fp32
    const ushort* __restrict__ w1t,  // [E][I][D] bf16
    const ushort* __restrict__ w3t,  // [E][I][D] bf16
    const int* __restrict__ g,
    ushort* __restrict__ h,          // [T][I] bf16
    int T, int D, int I, int E) {
  __shared__ ushort As[BM * BKE];
  __shared__ ushort B1s[BN * BKE];
  __shared__ ushort B3s[BN * BKE];

  const int RT = T / BM, CT = I / BN;
  int r, c;
  xcd_map(blockIdx.x, RT, CT, r, c);
  const int m0 = r * BM, n0 = c * BN;

  const int e = expert_of(g, E, m0);
  const ushort* b1p = w1t + (size_t)e * I * D;
  const ushort* b3p = w3t + (size_t)e * I * D;

  const int tid = threadIdx.x;
  const int lane = tid & 63, wave = tid >> 6;
  const int wr = wave >> 1, wc = wave & 1;

  const f32x4 zero = {0.f, 0.f, 0.f, 0.f};
  f32x4 acc1[4][4], acc3[4][4];
#pragma unroll
  for (int m = 0; m < 4; ++m)
#pragma unroll
    for (int n = 0; n < 4; ++n) { acc1[m][n] = zero; acc3[m][n] = zero; }

  const int arow = tid >> 4;    // 0..15
  const int acol4 = tid & 15;   // float4 column
  const int brow = lane >> 3;   // 0..7 within chunk
  const int bcol = (lane & 7) * 8;

  const int KT = D / BKE;
  for (int kt = 0; kt < KT; ++kt) {
    const int k0 = kt * BKE;
    __syncthreads();  // previous tile fully consumed
    // stage A (fp32 -> bf16, reg-staged)
#pragma unroll
    for (int i = 0; i < 8; ++i) {
      const int rr = arow + 16 * i;
      const float4 v = *reinterpret_cast<const float4*>(x + (size_t)(m0 + rr) * D + k0 + acol4 * 4);
      ushort4 u; u.x = f2bf(v.x); u.y = f2bf(v.y); u.z = f2bf(v.z); u.w = f2bf(v.w);
      *reinterpret_cast<ushort4*>(&As[rr * BKE + acol4 * 4]) = u;
    }
    // stage B1/B3 via global_load_lds (16B per lane, 1KB per wave-call)
#pragma unroll
    for (int q = 0; q < 4; ++q) {
      const int chunk = wave * 4 + q;
      const int nrow = chunk * 8 + brow;
      const ushort* g1 = b1p + (size_t)(n0 + nrow) * D + k0 + bcol;
      const ushort* g3 = b3p + (size_t)(n0 + nrow) * D + k0 + bcol;
      __builtin_amdgcn_global_load_lds((const __attribute__((address_space(1))) void*)g1,
                                       (__attribute__((address_space(3))) void*)&B1s[chunk * 512],
                                       16, 0, 0);
      __builtin_amdgcn_global_load_lds((const __attribute__((address_space(1))) void*)g3,
                                       (__attribute__((address_space(3))) void*)&B3s[chunk * 512],
                                       16, 0, 0);
    }
    __syncthreads();  // staging complete (implies vmcnt/lgkmcnt drain)
    // compute
#pragma unroll
    for (int kk = 0; kk < 2; ++kk) {
      const int kb = kk * 32 + (lane >> 4) * 8;
      bf16x8 a[4], b1[4], b3[4];
#pragma unroll
      for (int m = 0; m < 4; ++m)
        a[m] = *reinterpret_cast<const bf16x8*>(&As[(wr * 64 + m * 16 + (lane & 15)) * BKE + kb]);
#pragma unroll
      for (int n = 0; n < 4; ++n) {
        b1[n] = *reinterpret_cast<const bf16x8*>(&B1s[(wc * 64 + n * 16 + (lane & 15)) * BKE + kb]);
        b3[n] = *reinterpret_cast<const bf16x8*>(&B3s[(wc * 64 + n * 16 + (lane & 15)) * BKE + kb]);
      }
#pragma unroll
      for (int m = 0; m < 4; ++m)
#pragma unroll
        for (int n = 0; n < 4; ++n) {
          acc1[m][n] = __builtin_amdgcn_mfma_f32_16x16x32_bf16(a[m], b1[n], acc1[m][n], 0, 0, 0);
          acc3[m][n] = __builtin_amdgcn_mfma_f32_16x16x32_bf16(a[m], b3[n], acc3[m][n], 0, 0, 0);
        }
    }
  }
  // epilogue: SwiGLU, write h as bf16
#pragma unroll
  for (int m = 0; m < 4; ++m)
#pragma unroll
    for (int n = 0; n < 4; ++n)
#pragma unroll
      for (int rr = 0; rr < 4; ++rr) {
        const float v1 = acc1[m][n][rr];
        const float v3 = acc3[m][n][rr];
        const float sv = v1 / (1.f + __expf(-v1));
        const int row = m0 + wr * 64 + m * 16 + (lane >> 4) * 4 + rr;
        const int col = n0 + wc * 64 + n * 16 + (lane & 15);
        h[(size_t)row * I + col] = f2bf(sv * v3);
      }
}

// ---------------- GEMM2: out = h @ w2, fp32 out ----------------
__global__ __launch_bounds__(256) void k_gemm2(
    const ushort* __restrict__ h,    // [T][I] bf16
    const ushort* __restrict__ w2t,  // [E][D][I] bf16
    const int* __restrict__ g,
    float* __restrict__ out,         // [T][D] fp32
    int T, int D, int I, int E) {
  __shared__ ushort As[BM * BKE];
  __shared__ ushort Bs[BN * BKE];

  const int RT = T / BM, CT = D / BN;
  int r, c;
  xcd_map(blockIdx.x, RT, CT, r, c);
  const int m0 = r * BM, n0 = c * BN;

  const int e = expert_of(g, E, m0);
  const ushort* bp = w2t + (size_t)e * D * I;

  const int tid = threadIdx.x;
  const int lane = tid & 63, wave = tid >> 6;
  const int wr = wave >> 1, wc = wave & 1;

  const f32x4 zero = {0.f, 0.f, 0.f, 0.f};
  f32x4 acc[4][4];
#pragma unroll
  for (int m = 0; m < 4; ++m)
#pragma unroll
    for (int n = 0; n < 4; ++n) acc[m][n] = zero;

  const int brow = lane >> 3;
  const int bcol = (lane & 7) * 8;

  const int KT = I / BKE;
  for (int kt = 0; kt < KT; ++kt) {
    const int k0 = kt * BKE;
    __syncthreads();
#pragma unroll
    for (int q = 0; q < 4; ++q) {
      const int chunk = wave * 4 + q;
      const int row8 = chunk * 8 + brow;
      const ushort* ga = h + (size_t)(m0 + row8) * I + k0 + bcol;
      const ushort* gb = bp + (size_t)(n0 + row8) * I + k0 + bcol;
      __builtin_amdgcn_global_load_lds((const __attribute__((address_space(1))) void*)ga,
                                       (__attribute__((address_space(3))) void*)&As[chunk * 512],
                                       16, 0, 0);
      __builtin_amdgcn_global_load_lds((const __attribute__((address_space(1))) void*)gb,
                                       (__attribute__((address_space(3))) void*)&Bs[chunk * 512],
                                       16, 0, 0);
    }
    __syncthreads();
#pragma unroll
    for (int kk = 0; kk < 2; ++kk) {
      const int kb = kk * 32 + (lane >> 4) * 8;
      bf16x8 a[4], b[4];
#pragma unroll
      for (int m = 0; m < 4; ++m)
        a[m] = *reinterpret_cast<const bf16x8*>(&As[(wr * 64 + m * 16 + (lane & 15)) * BKE + kb]);
#pragma unroll
      for (int n = 0; n < 4; ++n)
        b[n] = *reinterpret_cast<const bf16x8*>(&Bs[(wc * 64 + n * 16 + (lane & 15)) * BKE + kb]);
#pragma unroll
      for (int m = 0; m < 4; ++m)
#pragma unroll
        for (int n = 0; n < 4; ++n)
          acc[m][n] = __builtin_amdgcn_mfma_f32_16x16x32_bf16(a[m], b[n], acc[m][n], 0, 0, 0);
    }
  }
#pragma unroll
  for (int m = 0; m < 4; ++m)
#pragma unroll
    for (int n = 0; n < 4; ++n)
#pragma unroll
      for (int rr = 0; rr < 4; ++rr) {
        const int row = m0 + wr * 64 + m * 16 + (lane >> 4) * 4 + rr;
        const int col = n0 + wc * 64 + n * 16 + (lane & 15);
        out[(size_t)row * D + col] = acc[m][n][rr];
      }
}

// ---------------- launch ----------------
extern "C" void kernel_launch(void* const* d_in, const int* in_sizes, int n_in,
                              void* d_out, int out_size, void* d_ws, size_t ws_size,
                              hipStream_t stream) {
  const float* x  = (const float*)d_in[0];
  const float* w1 = (const float*)d_in[1];
  const float* w2 = (const float*)d_in[2];
  const float* w3 = (const float*)d_in[3];
  const int*   g  = (const int*)d_in[4];

  const int E = in_sizes[4];
  const int D = 4096;
  const int I = 1024;
  const int T = in_sizes[0] / D;

  const size_t szW = (size_t)E * D * I * sizeof(ushort);  // 64 MB
  const size_t szH = (size_t)T * I * sizeof(ushort);      // 64 MB
  const size_t need = 2 * szW + szH;                      // 192 MB (w2t reuses w1t slot)
  if (ws_size < need) return;  // fail loudly via validation rather than corrupt memory

  char* ws = (char*)d_ws;
  ushort* w1t = (ushort*)ws;                 // slot 0 (reused by w2t later)
  ushort* w3t = (ushort*)(ws + szW);         // slot 1
  ushort* h   = (ushort*)(ws + 2 * szW);     // slot 2
  ushort* w2t = w1t;                         // reuse after gemm1

  float* out = (float*)d_out;
  dim3 blk(256);

  // weights transpose + convert: w1 [E][D][I] -> [E][I][D]; same for w3
  k_transpose_bf16<<<dim3(I / 64, D / 64, E), blk, 0, stream>>>(w1, w1t, D, I);
  k_transpose_bf16<<<dim3(I / 64, D / 64, E), blk, 0, stream>>>(w3, w3t, D, I);

  // GEMM1 fused SwiGLU -> h
  k_gemm1_swiglu<<<dim3((T / BM) * (I / BN)), blk, 0, stream>>>(x, w1t, w3t, g, h, T, D, I, E);

  // w2 [E][I][D] -> [E][D][I] into slot 0 (gemm1 already consumed w1t)
  k_transpose_bf16<<<dim3(D / 64, I / 64, E), blk, 0, stream>>>(w2, w2t, I, D);

  // GEMM2 -> out
  k_gemm2<<<dim3((T / BM) * (D / BN)), blk, 0, stream>>>(h, w2t, g, out, T, D, I, E);
}